// Round 12
// baseline (2495.895 us; speedup 1.0000x reference)
//
#include <hip/hip_runtime.h>
#include <hip/hip_bf16.h>
#include <stdint.h>

typedef __bf16 bf16_t;
typedef __bf16 bf16x8 __attribute__((ext_vector_type(8)));
typedef float  f32x4  __attribute__((ext_vector_type(4)));
typedef int    i32x4  __attribute__((ext_vector_type(4)));

#define T_STEPS 512
#define BATCH   64
#define EMBD    512
#define HID     1024
#define MROWS   (T_STEPS * BATCH)   // 32768
#define HSLOT   (BATCH * HID)       // 65536 elems = 131072 B per h slot
#define NBLK    128                 // LSTM blocks; each owns 8 hidden units

// ws layout
#define OFF_FLAGS 0u                    // 128 flag lines, 256B apart (8 dwords used each)
#define OFF_RING  32768u                // h ring: 2 slots * 128KB
#define OFF_E     (OFF_RING + 262144u)  // e bf16 [T*B][512] = 32MB

__device__ __forceinline__ int imin(int a, int b) { return a < b ? a : b; }

// ---------------- embedding gather: e[t*64+b][:] = bf16(emb[x[b][t]]) ----------------
__global__ __launch_bounds__(256) void k_gather(const int* __restrict__ x,
                                                const float* __restrict__ emb,
                                                bf16_t* __restrict__ e) {
  const int row  = blockIdx.x * 4 + (threadIdx.x >> 6);  // t*64+b
  const int lane = threadIdx.x & 63;
  const int t = row >> 6, b = row & 63;
  const int id = x[b * T_STEPS + t];
  const float* src = emb + (size_t)id * EMBD + lane * 8;
  float4 a = *(const float4*)src;
  float4 c = *(const float4*)(src + 4);
  bf16x8 o;
  o[0]=(bf16_t)a.x; o[1]=(bf16_t)a.y; o[2]=(bf16_t)a.z; o[3]=(bf16_t)a.w;
  o[4]=(bf16_t)c.x; o[5]=(bf16_t)c.y; o[6]=(bf16_t)c.z; o[7]=(bf16_t)c.w;
  *(bf16x8*)(e + (size_t)row * EMBD + lane * 8) = o;
}

// ---------------- persistent LSTM scan (r11 + distributed store / per-wave flags) ----
// 128 blocks x 512 threads. Block bb owns hidden units [bb*8,bb*8+8) = 32 gate rows.
// 8 waves = K-half s (2) x batch quarter w4 (4). W_hh B-frags hoisted to VGPRs
// (ZERO LDS on the h critical path). h ring block-major [blk][batch][unit8].
// NEW (r12): after gates, EACH wave stores its own 128B h-slice (2B/lane,
// contiguous), drains vmcnt(0), and plain-stores t+1 into dword w of its
// block's flag line — no hstage, no gather, no sync3, no intra-block fan-in.
// Wave 0 polls 8 dwords x 128 blocks (4x dwordx4 per lane), min + __all,
// __syncthreads releases block. 2 syncs/step steady state.
__global__ __launch_bounds__(512, 1) void k_lstm(const float* __restrict__ Whh,
                                                 const float* __restrict__ Wih,
                                                 const float* __restrict__ bih,
                                                 const float* __restrict__ bhh,
                                                 const bf16_t* __restrict__ e,
                                                 bf16_t* __restrict__ ring,
                                                 int* __restrict__ flags) {
  __shared__ __align__(16) char Ws[65536];   // [32][1024] bf16, XOR-swizzled (staging)
  __shared__ __align__(16) char Wi[32768];   // [32][512]  bf16, XOR-swizzled
  __shared__ float gb[2][2][64 * 33];        // [parity][K-half][batch][32 gates]
  __shared__ float bsh[32];
  const int tid = threadIdx.x;
  const int lane = tid & 63;
  const int w = tid >> 6;            // 0..7
  const int s = w >> 2;              // K-half
  const int w4 = w & 3;              // batch quarter
  const int bb = blockIdx.x;
  const int l15 = lane & 15, lq = lane >> 4;
  const int nmask = (l15 & 7) << 4;

  // stage W_hh slice: 32 rows x 1024 f32->bf16, swizzled
  for (int c0 = tid; c0 < 4096; c0 += 512) {
    int n = c0 >> 7, koff = c0 & 127;
    int grow = (n >> 3) * HID + bb * 8 + (n & 7);
    const float4* src = (const float4*)(Whh + (size_t)grow * HID + koff * 8);
    float4 a = src[0], b = src[1];
    bf16x8 v;
    v[0]=(bf16_t)a.x; v[1]=(bf16_t)a.y; v[2]=(bf16_t)a.z; v[3]=(bf16_t)a.w;
    v[4]=(bf16_t)b.x; v[5]=(bf16_t)b.y; v[6]=(bf16_t)b.z; v[7]=(bf16_t)b.w;
    *(bf16x8*)(Ws + n * 2048 + ((koff * 16) ^ ((n & 7) << 4))) = v;
  }
  // stage W_ih slice: 32 rows x 512
  for (int c0 = tid; c0 < 2048; c0 += 512) {
    int n = c0 >> 6, koff = c0 & 63;
    int grow = (n >> 3) * HID + bb * 8 + (n & 7);
    const float4* src = (const float4*)(Wih + (size_t)grow * EMBD + koff * 8);
    float4 a = src[0], b = src[1];
    bf16x8 v;
    v[0]=(bf16_t)a.x; v[1]=(bf16_t)a.y; v[2]=(bf16_t)a.z; v[3]=(bf16_t)a.w;
    v[4]=(bf16_t)b.x; v[5]=(bf16_t)b.y; v[6]=(bf16_t)b.z; v[7]=(bf16_t)b.w;
    *(bf16x8*)(Wi + n * 1024 + ((koff * 16) ^ ((n & 7) << 4))) = v;
  }
  if (tid < 32) {
    int g = (tid >> 3) * HID + bb * 8 + (tid & 7);
    bsh[tid] = bih[g] + bhh[g];
  }
  __syncthreads();

  // hoist loop-invariant W_hh B-fragments into VGPRs (once)
  bf16x8 wb0[16], wb1[16];
  {
    const char* wr0 = Ws + l15 * 2048;
    const char* wr1 = Ws + (16 + l15) * 2048;
    #pragma unroll
    for (int kk = 0; kk < 16; ++kk) {
      int off = ((s * 16 + kk) * 64 + lq * 16) ^ nmask;
      wb0[kk] = *(const bf16x8*)(wr0 + off);
      wb1[kk] = *(const bf16x8*)(wr1 + off);
    }
  }

  float c_st = 0.f;                         // per-thread (batch,unit) cell state
  const int un = lane & 7;
  const int gbatch = w * 8 + (lane >> 3);
  const int a_row = w4 * 16 + l15;          // batch row for MFMA A-frags
  const char* wi0 = Wi + l15 * 1024;
  const char* wi1 = Wi + (16 + l15) * 1024;
  const int* f0p = flags + lane * 64;       // poll base: block lane
  const int* f1p = flags + (64 + lane) * 64;

  for (int t = 0; t < T_STEPS; ++t) {
    const bf16_t* hp = ring + (size_t)(t & 1) * HSLOT;
    bf16_t* hn = ring + (size_t)((t + 1) & 1) * HSLOT;
    const int par = t & 1;

    f32x4 acc0 = {0.f, 0.f, 0.f, 0.f};
    f32x4 acc1 = {0.f, 0.f, 0.f, 0.f};

    // ---- e-part (h-independent; overlaps producer store/flag latency) ----
    {
      const bf16_t* ep = e + ((size_t)t * BATCH + a_row) * EMBD + s * 256 + lq * 8;
      #pragma unroll
      for (int kk = 0; kk < 8; ++kk) {
        bf16x8 a  = *(const bf16x8*)(ep + kk * 32);
        int off = ((s * 8 + kk) * 64 + lq * 16) ^ nmask;
        bf16x8 b0 = *(const bf16x8*)(wi0 + off);
        bf16x8 b1 = *(const bf16x8*)(wi1 + off);
        acc0 = __builtin_amdgcn_mfma_f32_16x16x32_bf16(a, b0, acc0, 0, 0, 0);
        acc1 = __builtin_amdgcn_mfma_f32_16x16x32_bf16(a, b1, acc1, 0, 0, 0);
      }
    }

    // ---- wave 0: poll 8 flag dwords x 128 blocks (2 blocks/lane) ----
    if (w == 0 && t > 0) {
      bool done;
      do {
        i32x4 a, b, c, d;
        asm volatile("global_load_dwordx4 %0, %1, off sc0 sc1"           : "=v"(a) : "v"(f0p) : "memory");
        asm volatile("global_load_dwordx4 %0, %1, off offset:16 sc0 sc1" : "=v"(b) : "v"(f0p) : "memory");
        asm volatile("global_load_dwordx4 %0, %1, off sc0 sc1"           : "=v"(c) : "v"(f1p) : "memory");
        asm volatile("global_load_dwordx4 %0, %1, off offset:16 sc0 sc1" : "=v"(d) : "v"(f1p) : "memory");
        asm volatile("s_waitcnt vmcnt(0)" ::: "memory");
        int m0 = imin(imin(imin(a[0], a[1]), imin(a[2], a[3])),
                      imin(imin(b[0], b[1]), imin(b[2], b[3])));
        int m1 = imin(imin(imin(c[0], c[1]), imin(c[2], c[3])),
                      imin(imin(d[0], d[1]), imin(d[2], d[3])));
        done = __all(imin(m0, m1) >= t);
        if (!done) __builtin_amdgcn_s_sleep(1);
      } while (!done);
    }
    __syncthreads();                      // release all waves into h-part
    __builtin_amdgcn_sched_barrier(0);

    // ---- h-part: 16 sc0sc1 b128 loads, vmcnt-pipelined into 32 reg-B MFMA ----
    bf16x8 hv[16];
    const bf16_t* bp = hp + ((size_t)(s * 64 + lq) << 9) + a_row * 8;
    #pragma unroll
    for (int kk = 0; kk < 16; ++kk) {
      const bf16_t* ad = bp + kk * 2048;
      asm volatile("global_load_dwordx4 %0, %1, off sc0 sc1"
                   : "=v"(hv[kk]) : "v"(ad) : "memory");
    }
    asm volatile("s_waitcnt vmcnt(8)" ::: "memory");
    __builtin_amdgcn_sched_barrier(0);
    #pragma unroll
    for (int kk = 0; kk < 8; ++kk) {
      acc0 = __builtin_amdgcn_mfma_f32_16x16x32_bf16(hv[kk], wb0[kk], acc0, 0, 0, 0);
      acc1 = __builtin_amdgcn_mfma_f32_16x16x32_bf16(hv[kk], wb1[kk], acc1, 0, 0, 0);
    }
    asm volatile("s_waitcnt vmcnt(0)" ::: "memory");
    __builtin_amdgcn_sched_barrier(0);
    #pragma unroll
    for (int kk = 8; kk < 16; ++kk) {
      acc0 = __builtin_amdgcn_mfma_f32_16x16x32_bf16(hv[kk], wb0[kk], acc0, 0, 0, 0);
      acc1 = __builtin_amdgcn_mfma_f32_16x16x32_bf16(hv[kk], wb1[kk], acc1, 0, 0, 0);
    }

    // ---- publish partials, sync ----
    #pragma unroll
    for (int r = 0; r < 4; ++r) {
      int brow = (w4 * 16 + lq * 4 + r) * 33;
      gb[par][s][brow + l15]      = acc0[r];
      gb[par][s][brow + 16 + l15] = acc1[r];
    }
    __syncthreads();

    // ---- gates (1 cell/thread) -> own 2B store -> own drain -> own wave flag ----
    {
      const float* g0 = &gb[par][0][gbatch * 33];
      const float* g1 = &gb[par][1][gbatch * 33];
      float gi = g0[un]      + g1[un]      + bsh[un];
      float gf = g0[8 + un]  + g1[8 + un]  + bsh[8 + un];
      float gg = g0[16 + un] + g1[16 + un] + bsh[16 + un];
      float go = g0[24 + un] + g1[24 + un] + bsh[24 + un];
      float i_ = 1.f / (1.f + __expf(-gi));
      float f_ = 1.f / (1.f + __expf(-gf));
      float g_ = 1.f - 2.f / (1.f + __expf(2.f * gg));   // tanh
      float o_ = 1.f / (1.f + __expf(-go));
      c_st = f_ * c_st + i_ * g_;
      union { bf16_t h; unsigned short u; } pk;
      pk.h = (bf16_t)(o_ * (1.f - 2.f / (1.f + __expf(2.f * c_st))));
      unsigned int sval = pk.u;
      bf16_t* dst = hn + (size_t)bb * 512 + tid;      // wave slice contiguous 128B
      asm volatile("global_store_short %0, %1, off sc0 sc1"
                   :: "v"(dst), "v"(sval) : "memory");
      asm volatile("s_waitcnt vmcnt(0)" ::: "memory"); // this wave's slice at L3
      if (lane == 0) {
        int fv = t + 1;
        const int* fdst = flags + bb * 64 + w;         // dword w of block's line
        asm volatile("global_store_dword %0, %1, off sc0 sc1"
                     :: "v"(fdst), "v"(fv) : "memory");
      }
    }
    // no tail sync: waves run ahead into e-part(t+1); parity gb + monotone flags
  }
}

// ---------------- final FC: out[b][j] = h[b] . fc_w[j] + fc_b[j] ----------------
// h is block-major: h[(j>>3)*512 + b*8 + (j&7)]
__global__ __launch_bounds__(256) void k_fc(const bf16_t* __restrict__ h,
                                            const float* __restrict__ fcw,
                                            const float* __restrict__ fcb,
                                            float* __restrict__ out) {
  __shared__ float hs[HID];
  const int b = blockIdx.x >> 2, js = blockIdx.x & 3;
  const int tid = threadIdx.x;
  #pragma unroll
  for (int i = 0; i < 4; ++i) {
    int j = tid * 4 + i;
    hs[j] = (float)h[((j >> 3) << 9) + b * 8 + (j & 7)];
  }
  __syncthreads();
  int j = js * 256 + tid;
  const float4* wr = (const float4*)(fcw + (size_t)j * HID);
  float s = 0.f;
  for (int k = 0; k < 256; ++k) {
    float4 wv = wr[k];
    s += hs[k * 4] * wv.x + hs[k * 4 + 1] * wv.y + hs[k * 4 + 2] * wv.z + hs[k * 4 + 3] * wv.w;
  }
  out[b * HID + j] = s + fcb[j];
}

extern "C" void kernel_launch(void* const* d_in, const int* in_sizes, int n_in,
                              void* d_out, int out_size, void* d_ws, size_t ws_size,
                              hipStream_t stream) {
  const int*   x   = (const int*)  d_in[0];
  const float* emb = (const float*)d_in[1];
  const float* Wih = (const float*)d_in[2];
  const float* bih = (const float*)d_in[3];
  const float* Whh = (const float*)d_in[4];
  const float* bhh = (const float*)d_in[5];
  const float* fcw = (const float*)d_in[6];
  const float* fcb = (const float*)d_in[7];
  float* out = (float*)d_out;

  char* ws = (char*)d_ws;
  int*    flags = (int*)   (ws + OFF_FLAGS);
  bf16_t* ring  = (bf16_t*)(ws + OFF_RING);
  bf16_t* e_b   = (bf16_t*)(ws + OFF_E);
  bf16_t* hfin  = ring;   // T_STEPS even -> final h in slot 0

  // zero flags + h slot 0 every call (graph-replay safe)
  (void)hipMemsetAsync(ws, 0, OFF_RING + (size_t)HSLOT * sizeof(bf16_t), stream);

  k_gather<<<MROWS / 4, 256, 0, stream>>>(x, emb, e_b);
  k_lstm<<<NBLK, 512, 0, stream>>>(Whh, Wih, bih, bhh, e_b, ring, flags);
  k_fc<<<BATCH * 4, 256, 0, stream>>>(hfin, fcw, fcb, out);
}

// Round 13
// 2299.281 us; speedup vs baseline: 1.0855x; 1.0855x over previous
//
#include <hip/hip_runtime.h>
#include <hip/hip_bf16.h>
#include <stdint.h>

typedef __bf16 bf16_t;
typedef __bf16 bf16x8 __attribute__((ext_vector_type(8)));
typedef float  f32x4  __attribute__((ext_vector_type(4)));
typedef uint32_t u32x4 __attribute__((ext_vector_type(4)));

#define T_STEPS 512
#define BATCH   64
#define EMBD    512
#define HID     1024
#define MROWS   (T_STEPS * BATCH)   // 32768
#define HSLOT   (BATCH * HID)       // 65536 elems = 131072 B per h slot
#define NBLK    128                 // LSTM blocks; each owns 8 hidden units

// ws layout
#define OFF_FLAGS 0u                    // 128 flags, 256B apart = 32KB
#define OFF_RING  32768u                // h ring: 2 slots * 128KB
#define OFF_E     (OFF_RING + 262144u)  // e bf16 [T*B][512] = 32MB

// ---------------- embedding gather: e[t*64+b][:] = bf16(emb[x[b][t]]) ----------------
__global__ __launch_bounds__(256) void k_gather(const int* __restrict__ x,
                                                const float* __restrict__ emb,
                                                bf16_t* __restrict__ e) {
  const int row  = blockIdx.x * 4 + (threadIdx.x >> 6);  // t*64+b
  const int lane = threadIdx.x & 63;
  const int t = row >> 6, b = row & 63;
  const int id = x[b * T_STEPS + t];
  const float* src = emb + (size_t)id * EMBD + lane * 8;
  float4 a = *(const float4*)src;
  float4 c = *(const float4*)(src + 4);
  bf16x8 o;
  o[0]=(bf16_t)a.x; o[1]=(bf16_t)a.y; o[2]=(bf16_t)a.z; o[3]=(bf16_t)a.w;
  o[4]=(bf16_t)c.x; o[5]=(bf16_t)c.y; o[6]=(bf16_t)c.z; o[7]=(bf16_t)c.w;
  *(bf16x8*)(e + (size_t)row * EMBD + lane * 8) = o;
}

// ---------------- persistent LSTM scan (r11 producer + split-phase consumer) ----------
// 128 blocks x 512 threads. Block bb owns hidden units [bb*8,bb*8+8) = 32 gate rows.
// 8 waves = K-half s (2) x batch quarter w4 (4). W_hh B-frags hoisted to VGPRs
// (ZERO LDS on the h critical path). h ring block-major [blk][batch][unit8].
// KEY (r13): a wave with K-half s reads h ONLY from source blocks [s*64,s*64+64).
// Wave 0 polls flags 0-63 (1/lane) -> LDS token A; wave 4 polls flags 64-127 ->
// token B; s=0 waves spin on A, s=1 on B. Each half starts loads as soon as ITS
// producers landed — the other half's straggler hides under load+MFMA overlap.
// Producer: gates 1/thread -> hstage; wave 0 gathers 1KB, ONE sc0sc1 burst
// store, vmcnt(0) drain, plain flag store (t+1). 2 block syncs/step.
__global__ __launch_bounds__(512, 1) void k_lstm(const float* __restrict__ Whh,
                                                 const float* __restrict__ Wih,
                                                 const float* __restrict__ bih,
                                                 const float* __restrict__ bhh,
                                                 const bf16_t* __restrict__ e,
                                                 bf16_t* __restrict__ ring,
                                                 int* __restrict__ flags) {
  __shared__ __align__(16) char Ws[65536];   // [32][1024] bf16, XOR-swizzled (staging)
  __shared__ __align__(16) char Wi[32768];   // [32][512]  bf16, XOR-swizzled
  __shared__ float gb[2][2][64 * 33];        // [parity][K-half][batch][32 gates]
  __shared__ float bsh[32];
  __shared__ bf16_t hstage[512];             // [batch][unit8]
  __shared__ int tok[2];                     // per-K-half ready tokens (monotone = t)
  const int tid = threadIdx.x;
  const int lane = tid & 63;
  const int w = tid >> 6;            // 0..7
  const int s = w >> 2;              // K-half
  const int w4 = w & 3;              // batch quarter
  const int bb = blockIdx.x;
  const int l15 = lane & 15, lq = lane >> 4;
  const int nmask = (l15 & 7) << 4;

  // stage W_hh slice: 32 rows x 1024 f32->bf16, swizzled
  for (int c0 = tid; c0 < 4096; c0 += 512) {
    int n = c0 >> 7, koff = c0 & 127;
    int grow = (n >> 3) * HID + bb * 8 + (n & 7);
    const float4* src = (const float4*)(Whh + (size_t)grow * HID + koff * 8);
    float4 a = src[0], b = src[1];
    bf16x8 v;
    v[0]=(bf16_t)a.x; v[1]=(bf16_t)a.y; v[2]=(bf16_t)a.z; v[3]=(bf16_t)a.w;
    v[4]=(bf16_t)b.x; v[5]=(bf16_t)b.y; v[6]=(bf16_t)b.z; v[7]=(bf16_t)b.w;
    *(bf16x8*)(Ws + n * 2048 + ((koff * 16) ^ ((n & 7) << 4))) = v;
  }
  // stage W_ih slice: 32 rows x 512
  for (int c0 = tid; c0 < 2048; c0 += 512) {
    int n = c0 >> 6, koff = c0 & 63;
    int grow = (n >> 3) * HID + bb * 8 + (n & 7);
    const float4* src = (const float4*)(Wih + (size_t)grow * EMBD + koff * 8);
    float4 a = src[0], b = src[1];
    bf16x8 v;
    v[0]=(bf16_t)a.x; v[1]=(bf16_t)a.y; v[2]=(bf16_t)a.z; v[3]=(bf16_t)a.w;
    v[4]=(bf16_t)b.x; v[5]=(bf16_t)b.y; v[6]=(bf16_t)b.z; v[7]=(bf16_t)b.w;
    *(bf16x8*)(Wi + n * 1024 + ((koff * 16) ^ ((n & 7) << 4))) = v;
  }
  if (tid < 32) {
    int g = (tid >> 3) * HID + bb * 8 + (tid & 7);
    bsh[tid] = bih[g] + bhh[g];
  }
  if (tid < 2) tok[tid] = 0;
  __syncthreads();

  // hoist loop-invariant W_hh B-fragments into VGPRs (once)
  bf16x8 wb0[16], wb1[16];
  {
    const char* wr0 = Ws + l15 * 2048;
    const char* wr1 = Ws + (16 + l15) * 2048;
    #pragma unroll
    for (int kk = 0; kk < 16; ++kk) {
      int off = ((s * 16 + kk) * 64 + lq * 16) ^ nmask;
      wb0[kk] = *(const bf16x8*)(wr0 + off);
      wb1[kk] = *(const bf16x8*)(wr1 + off);
    }
  }

  float c_st = 0.f;                         // per-thread (batch,unit) cell state
  const int un = lane & 7;
  const int gbatch = w * 8 + (lane >> 3);
  const int a_row = w4 * 16 + l15;          // batch row for MFMA A-frags
  const char* wi0 = Wi + l15 * 1024;
  const char* wi1 = Wi + (16 + l15) * 1024;

  for (int t = 0; t < T_STEPS; ++t) {
    const bf16_t* hp = ring + (size_t)(t & 1) * HSLOT;
    bf16_t* hn = ring + (size_t)((t + 1) & 1) * HSLOT;
    const int par = t & 1;

    f32x4 acc0 = {0.f, 0.f, 0.f, 0.f};
    f32x4 acc1 = {0.f, 0.f, 0.f, 0.f};

    // ---- e-part (h-independent; overlaps producer store/flag latency) ----
    {
      const bf16_t* ep = e + ((size_t)t * BATCH + a_row) * EMBD + s * 256 + lq * 8;
      #pragma unroll
      for (int kk = 0; kk < 8; ++kk) {
        bf16x8 a  = *(const bf16x8*)(ep + kk * 32);
        int off = ((s * 8 + kk) * 64 + lq * 16) ^ nmask;
        bf16x8 b0 = *(const bf16x8*)(wi0 + off);
        bf16x8 b1 = *(const bf16x8*)(wi1 + off);
        acc0 = __builtin_amdgcn_mfma_f32_16x16x32_bf16(a, b0, acc0, 0, 0, 0);
        acc1 = __builtin_amdgcn_mfma_f32_16x16x32_bf16(a, b1, acc1, 0, 0, 0);
      }
    }

    // ---- split-phase readiness: wave 0 -> flags[0..63] -> tok[0];
    //      wave 4 -> flags[64..127] -> tok[1]; other waves LDS-spin own half ----
    if (t > 0) {
      if (w == 0 || w == 4) {
        const int base = (w == 0) ? 0 : 64;
        bool done;
        do {
          int cv = __hip_atomic_load(flags + (base + lane) * 64,
                                     __ATOMIC_RELAXED, __HIP_MEMORY_SCOPE_AGENT);
          done = __all(cv >= t);
          if (!done) __builtin_amdgcn_s_sleep(1);
        } while (!done);
        __hip_atomic_store(&tok[base >> 6], t, __ATOMIC_RELEASE, __HIP_MEMORY_SCOPE_WORKGROUP);
      } else {
        while (__hip_atomic_load(&tok[s], __ATOMIC_ACQUIRE, __HIP_MEMORY_SCOPE_WORKGROUP) < t)
          __builtin_amdgcn_s_sleep(1);
      }
    }
    __builtin_amdgcn_sched_barrier(0);

    // ---- h-part: 16 sc0sc1 b128 loads (sources [s*64,s*64+64) only),
    //      vmcnt-pipelined into 32 reg-B MFMA ----
    bf16x8 hv[16];
    const bf16_t* bp = hp + ((size_t)(s * 64 + lq) << 9) + a_row * 8;
    #pragma unroll
    for (int kk = 0; kk < 16; ++kk) {
      const bf16_t* ad = bp + kk * 2048;     // source block (s*64 + kk*4 + lq)
      asm volatile("global_load_dwordx4 %0, %1, off sc0 sc1"
                   : "=v"(hv[kk]) : "v"(ad) : "memory");
    }
    asm volatile("s_waitcnt vmcnt(8)" ::: "memory");
    __builtin_amdgcn_sched_barrier(0);
    #pragma unroll
    for (int kk = 0; kk < 8; ++kk) {
      acc0 = __builtin_amdgcn_mfma_f32_16x16x32_bf16(hv[kk], wb0[kk], acc0, 0, 0, 0);
      acc1 = __builtin_amdgcn_mfma_f32_16x16x32_bf16(hv[kk], wb1[kk], acc1, 0, 0, 0);
    }
    asm volatile("s_waitcnt vmcnt(0)" ::: "memory");
    __builtin_amdgcn_sched_barrier(0);
    #pragma unroll
    for (int kk = 8; kk < 16; ++kk) {
      acc0 = __builtin_amdgcn_mfma_f32_16x16x32_bf16(hv[kk], wb0[kk], acc0, 0, 0, 0);
      acc1 = __builtin_amdgcn_mfma_f32_16x16x32_bf16(hv[kk], wb1[kk], acc1, 0, 0, 0);
    }

    // ---- publish partials, sync ----
    #pragma unroll
    for (int r = 0; r < 4; ++r) {
      int brow = (w4 * 16 + lq * 4 + r) * 33;
      gb[par][s][brow + l15]      = acc0[r];
      gb[par][s][brow + 16 + l15] = acc1[r];
    }
    __syncthreads();

    // ---- gates: distributed, one (batch,unit) per thread ----
    {
      const float* g0 = &gb[par][0][gbatch * 33];
      const float* g1 = &gb[par][1][gbatch * 33];
      float gi = g0[un]      + g1[un]      + bsh[un];
      float gf = g0[8 + un]  + g1[8 + un]  + bsh[8 + un];
      float gg = g0[16 + un] + g1[16 + un] + bsh[16 + un];
      float go = g0[24 + un] + g1[24 + un] + bsh[24 + un];
      float i_ = 1.f / (1.f + __expf(-gi));
      float f_ = 1.f / (1.f + __expf(-gf));
      float g_ = 1.f - 2.f / (1.f + __expf(2.f * gg));   // tanh
      float o_ = 1.f / (1.f + __expf(-go));
      c_st = f_ * c_st + i_ * g_;
      hstage[tid] = (bf16_t)(o_ * (1.f - 2.f / (1.f + __expf(2.f * c_st))));
    }
    __syncthreads();

    // ---- wave 0: gather 1KB, ONE burst store, drain, plain flag store ----
    if (w == 0) {
      u32x4 val = *(const u32x4*)(hstage + lane * 8);
      bf16_t* dst = hn + (size_t)bb * 512 + lane * 8;
      asm volatile("global_store_dwordx4 %0, %1, off sc0 sc1"
                   :: "v"(dst), "v"(val) : "memory");
      asm volatile("s_waitcnt vmcnt(0)" ::: "memory");   // h visible at L3
      if (lane == 0) {
        int fv = t + 1;
        const int* fdst = flags + bb * 64;
        asm volatile("global_store_dword %0, %1, off sc0 sc1"
                     :: "v"(fdst), "v"(fv) : "memory");
      }
    }
    // waves run ahead into e-part(t+1); parity gb + monotone tokens/flags keep it safe
  }
}

// ---------------- final FC: out[b][j] = h[b] . fc_w[j] + fc_b[j] ----------------
// h is block-major: h[(j>>3)*512 + b*8 + (j&7)]
__global__ __launch_bounds__(256) void k_fc(const bf16_t* __restrict__ h,
                                            const float* __restrict__ fcw,
                                            const float* __restrict__ fcb,
                                            float* __restrict__ out) {
  __shared__ float hs[HID];
  const int b = blockIdx.x >> 2, js = blockIdx.x & 3;
  const int tid = threadIdx.x;
  #pragma unroll
  for (int i = 0; i < 4; ++i) {
    int j = tid * 4 + i;
    hs[j] = (float)h[((j >> 3) << 9) + b * 8 + (j & 7)];
  }
  __syncthreads();
  int j = js * 256 + tid;
  const float4* wr = (const float4*)(fcw + (size_t)j * HID);
  float s = 0.f;
  for (int k = 0; k < 256; ++k) {
    float4 wv = wr[k];
    s += hs[k * 4] * wv.x + hs[k * 4 + 1] * wv.y + hs[k * 4 + 2] * wv.z + hs[k * 4 + 3] * wv.w;
  }
  out[b * HID + j] = s + fcb[j];
}

extern "C" void kernel_launch(void* const* d_in, const int* in_sizes, int n_in,
                              void* d_out, int out_size, void* d_ws, size_t ws_size,
                              hipStream_t stream) {
  const int*   x   = (const int*)  d_in[0];
  const float* emb = (const float*)d_in[1];
  const float* Wih = (const float*)d_in[2];
  const float* bih = (const float*)d_in[3];
  const float* Whh = (const float*)d_in[4];
  const float* bhh = (const float*)d_in[5];
  const float* fcw = (const float*)d_in[6];
  const float* fcb = (const float*)d_in[7];
  float* out = (float*)d_out;

  char* ws = (char*)d_ws;
  int*    flags = (int*)   (ws + OFF_FLAGS);
  bf16_t* ring  = (bf16_t*)(ws + OFF_RING);
  bf16_t* e_b   = (bf16_t*)(ws + OFF_E);
  bf16_t* hfin  = ring;   // T_STEPS even -> final h in slot 0

  // zero flags + h slot 0 every call (graph-replay safe)
  (void)hipMemsetAsync(ws, 0, OFF_RING + (size_t)HSLOT * sizeof(bf16_t), stream);

  k_gather<<<MROWS / 4, 256, 0, stream>>>(x, emb, e_b);
  k_lstm<<<NBLK, 512, 0, stream>>>(Whh, Wih, bih, bhh, e_b, ring, flags);
  k_fc<<<BATCH * 4, 256, 0, stream>>>(hfin, fcw, fcb, out);
}